// Round 9
// baseline (74.626 us; speedup 1.0000x reference)
//
#include <hip/hip_runtime.h>
#include <math.h>

// OT_Loss3: batched Sinkhorn (B=8, N_PTS=1024, M=4096, REG=10).
// K = Ky (x) Kx separable; 1-D factors rank-4 via Taylor of exp(x*c/5).
// ONE WAVE PER IMAGE (8 blocks x 64 threads): lane = one grid row (64 cells,
// By + nd row in registers) + 16 points. All 4x4-core reductions are in-wave
// shuffle butterflies: no __syncthreads, no LDS atomics, bit-deterministic.
// Folding (R6 lesson): gammas folded into POINT factors only; cell factors
// raw; S core = RAW S6 low block. NITER=3 (worst-case resid ~0.06 << 0.31).
// Cross-block combine: R4-R7-proven device-scope counter (cooperative launch
// silently failed in R8 -- never again without a fallback).

__device__ __forceinline__ float rcpf(float x) {
    return __builtin_amdgcn_rcpf(x);   // ~1e-7 rel err, fine for Sinkhorn
}
__device__ __forceinline__ float gamf(int p) {
    return (p == 0) ? 1.0f : (p == 1) ? 0.2f : (p == 2) ? 0.02f : (1.0f/750.0f);
}
__device__ __forceinline__ constexpr int brev4(int k) {
    return ((k&1)<<3) | ((k&2)<<1) | ((k&4)>>1) | ((k&8)>>3);
}
__device__ __forceinline__ float fsel(float4 v, int j) {
    return (j==0) ? v.x : (j==1) ? v.y : (j==2) ? v.z : v.w;
}

// Split-butterfly reduce of 16 per-lane values over 64 lanes:
// lane's result = total of logical index brev4(lane&15).
__device__ __forceinline__ float reduce16(float acc[16], int lane) {
    #pragma unroll
    for (int s = 0; s < 4; ++s) {
        const int m = 1 << s;
        const int h = 8 >> s;
        const bool hi = (lane & m) != 0;
        #pragma unroll
        for (int k = 0; k < h; ++k) {
            float send = hi ? acc[k]   : acc[k+h];
            float keep = hi ? acc[k+h] : acc[k];
            acc[k] = keep + __shfl_xor(send, m, 64);
        }
    }
    float r = acc[0];
    r += __shfl_xor(r, 16, 64);
    r += __shfl_xor(r, 32, 64);
    return r;
}
// All lanes end with the full 16 sums (reduce + static-lane gather).
__device__ __forceinline__ void allred16(float v[16], int lane) {
    float r = reduce16(v, lane);
    #pragma unroll
    for (int k = 0; k < 16; ++k)
        v[k] = __shfl(r, brev4(k), 64);
}

// wd contribution of one point (R7-validated formula, verbatim).
// S4 = RAW S6 low block; EXT[a2*4+q]=S6[4+a2][q]; EXT[8+p*2+b']=S6[p][4+b'].
__device__ __forceinline__ float wd_point2(const float Axe[6], const float Aye[6],
                                           const float Axg[4], const float Ayg[4],
                                           float u, const float* __restrict__ S4,
                                           const float* __restrict__ EXT) {
    float adx[6], ady[6];
    #pragma unroll
    for (int b = 0; b < 6; ++b) {
        float vx = 0.f, vy = 0.f;
        if (b <= 3)           { vx += gamf(b)*Axe[b+2];        vy += gamf(b)*Aye[b+2]; }
        if (b >= 1 && b <= 4) { vx -= 2.0f*gamf(b-1)*Axe[b];   vy -= 2.0f*gamf(b-1)*Aye[b]; }
        if (b >= 2)           { vx += gamf(b-2)*Axe[b-2];      vy += gamf(b-2)*Aye[b-2]; }
        adx[b] = vx; ady[b] = vy;
    }
    float t1 = 0.f, t2 = 0.f;
    #pragma unroll
    for (int a = 0; a < 4; ++a) {
        float h1 = S4[a*4+0]*Axg[0] + S4[a*4+1]*Axg[1]
                 + S4[a*4+2]*Axg[2] + S4[a*4+3]*Axg[3];
        t1 += ady[a]*h1;
        float h2 = S4[a*4+0]*adx[0] + S4[a*4+1]*adx[1]
                 + S4[a*4+2]*adx[2] + S4[a*4+3]*adx[3]
                 + EXT[8+a*2+0]*adx[4] + EXT[8+a*2+1]*adx[5];
        t2 += Ayg[a]*h2;
    }
    #pragma unroll
    for (int a2 = 0; a2 < 2; ++a2) {
        float h1 = EXT[a2*4+0]*Axg[0] + EXT[a2*4+1]*Axg[1]
                 + EXT[a2*4+2]*Axg[2] + EXT[a2*4+3]*Axg[3];
        t1 += ady[4+a2]*h1;
    }
    return u*(t1 + t2);
}

__global__ __launch_bounds__(64, 1) void ot_main(
    const float* __restrict__ nd_g, const float* __restrict__ ud_g,
    const float* __restrict__ pts_g, const float* __restrict__ vp_g,
    float* __restrict__ ws, int* __restrict__ cnt, float* __restrict__ out)
{
    const int img  = blockIdx.x;
    const int lane = threadIdx.x;           // 0..63, one wave per block
    const float* nd  = nd_g  + img*4096;
    const float* ud  = ud_g  + img*4096;
    const float* pts = pts_g + img*2048;
    const float* vp  = vp_g  + img*4096;

    __shared__ __align__(16) float4 BeT4[64];   // column basis table (1 KB)

    // ---- cells setup: lane owns row jy = lane ----
    const float cy  = (float)(8*lane + 4) * (1.0f/256.0f) - 1.0f;
    const float eyg = expf(-0.1f*cy*cy);
    float By[4];
    By[0]=eyg; By[1]=eyg*cy; By[2]=By[1]*cy; By[3]=By[2]*cy;
    BeT4[lane] = make_float4(By[0], By[1], By[2], By[3]);
    // same-wave LDS write->read: lockstep wave, lgkmcnt ordering, no barrier

    float4 brv[16];                              // nd row in registers
    #pragma unroll
    for (int k = 0; k < 16; ++k) brv[k] = ((const float4*)nd)[lane*16 + k];

    // ---- points setup: 16 points per lane (coalesced float2 loads) ----
    float px[16], py[16], pex[16], pey[16];
    #pragma unroll
    for (int k = 0; k < 16; ++k) {
        float2 p = ((const float2*)pts)[lane + 64*k];
        float x = p.x*(1.0f/256.0f)-1.0f, y = p.y*(1.0f/256.0f)-1.0f;
        px[k]=x; py[k]=y;
        pex[k]=expf(-0.1f*x*x); pey[k]=expf(-0.1f*y*y);
    }

    // ---- S0 from v0 = v_pred ----
    float Score[16];
    {
        float sx[4] = {0.f,0.f,0.f,0.f};
        #pragma unroll
        for (int k = 0; k < 16; ++k) {
            float4 v4 = ((const float4*)vp)[lane*16 + k];
            #pragma unroll
            for (int j = 0; j < 4; ++j) {
                float4 bx = BeT4[4*k+j];
                float w = fsel(v4, j);
                sx[0]+=w*bx.x; sx[1]+=w*bx.y; sx[2]+=w*bx.z; sx[3]+=w*bx.w;
            }
        }
        #pragma unroll
        for (int p = 0; p < 4; ++p)
            #pragma unroll
            for (int q = 0; q < 4; ++q) Score[p*4+q] = By[p]*sx[q];
        allred16(Score, lane);
    }

    float up[16], u3[16], Tc[16];

    #pragma unroll 1
    for (int it = 0; it < 3; ++it) {
        // ---- points: u_n = a/(Ayg^T S Axg);  T += u_n Ayg Axg^T ----
        #pragma unroll
        for (int k2 = 0; k2 < 16; ++k2) Tc[k2] = 0.f;
        #pragma unroll
        for (int k = 0; k < 16; ++k) {
            float x = px[k], ex = pex[k], y = py[k], ey = pey[k];
            float x2 = x*x, y2 = y*y;
            float Axg[4] = {ex, 0.2f*ex*x, 0.02f*ex*x2, (1.0f/750.0f)*ex*x2*x};
            float Ayg[4] = {ey, 0.2f*ey*y, 0.02f*ey*y2, (1.0f/750.0f)*ey*y2*y};
            float kv = 0.f;
            #pragma unroll
            for (int p = 0; p < 4; ++p) {
                float h = Score[p*4+0]*Axg[0] + Score[p*4+1]*Axg[1]
                        + Score[p*4+2]*Axg[2] + Score[p*4+3]*Axg[3];
                kv += Ayg[p]*h;
            }
            float u = (1.0f/1024.0f)*rcpf(kv + 1e-16f);
            if (it == 0) up[k] = u;
            if (it == 2) u3[k] = u;
            #pragma unroll
            for (int p = 0; p < 4; ++p) {
                float cu = u*Ayg[p];
                Tc[p*4+0]+=cu*Axg[0]; Tc[p*4+1]+=cu*Axg[1];
                Tc[p*4+2]+=cu*Axg[2]; Tc[p*4+3]+=cu*Axg[3];
            }
        }
        allred16(Tc, lane);

        if (it < 2) {
            // ---- cells: v_c = b_c / (By^T T Bx_c); S = sum v By Bx^T ----
            float h[4];
            #pragma unroll
            for (int q = 0; q < 4; ++q)
                h[q] = By[0]*Tc[0*4+q] + By[1]*Tc[1*4+q]
                     + By[2]*Tc[2*4+q] + By[3]*Tc[3*4+q];
            float sx[4] = {0.f,0.f,0.f,0.f};
            #pragma unroll
            for (int k = 0; k < 16; ++k) {
                float4 b4 = brv[k];
                #pragma unroll
                for (int j = 0; j < 4; ++j) {
                    float4 bx = BeT4[4*k+j];
                    float R = h[0]*bx.x + h[1]*bx.y + h[2]*bx.z + h[3]*bx.w;
                    float w = fsel(b4, j) * rcpf(R + 1e-16f);
                    sx[0]+=w*bx.x; sx[1]+=w*bx.y; sx[2]+=w*bx.z; sx[3]+=w*bx.w;
                }
            }
            #pragma unroll
            for (int p = 0; p < 4; ++p)
                #pragma unroll
                for (int q = 0; q < 4; ++q) Score[p*4+q] = By[p]*sx[q];
            allred16(Score, lane);
        }
    }

    // ---- final fused cells pass (T3 = Tc): v3, beta, S_final, EXT ----
    float h[4];
    #pragma unroll
    for (int q = 0; q < 4; ++q)
        h[q] = By[0]*Tc[0*4+q] + By[1]*Tc[1*4+q]
             + By[2]*Tc[2*4+q] + By[3]*Tc[3*4+q];
    float sx[4] = {0.f,0.f,0.f,0.f};
    float sx4 = 0.f, sx5 = 0.f;
    float nb=0.f, sud=0.f, sudb=0.f, svpv=0.f, svpvp=0.f, svv=0.f;
    #pragma unroll
    for (int k = 0; k < 16; ++k) {
        float4 b4  = brv[k];
        float4 u4  = ((const float4*)ud)[lane*16 + k];
        float4 vp4 = ((const float4*)vp)[lane*16 + k];
        #pragma unroll
        for (int j = 0; j < 4; ++j) {
            const int c = 4*k + j;
            float bc  = fsel(b4, j);
            float udc = fsel(u4, j);
            float vpc = fsel(vp4, j);
            float4 bx = BeT4[c];
            float R = h[0]*bx.x + h[1]*bx.y + h[2]*bx.z + h[3]*bx.w;
            float w = bc * rcpf(R + 1e-16f);
            float beta = 10.0f*logf(w + 1e-16f);
            nb    += bc*beta;
            sud   += udc;
            sudb  += udc*beta;
            svpv  += vpc*w;
            svpvp += vpc*vpc;
            svv   += w*w;
            sx[0]+=w*bx.x; sx[1]+=w*bx.y; sx[2]+=w*bx.z; sx[3]+=w*bx.w;
            const float cx = (float)(8*c + 4)*(1.0f/256.0f) - 1.0f;
            float b4p = bx.w*cx;            // ex*cx^4
            sx4 += w*b4p; sx5 += w*b4p*cx;  // ex*cx^5
        }
    }
    float SF[16], EXTv[16];
    #pragma unroll
    for (int p = 0; p < 4; ++p)
        #pragma unroll
        for (int q = 0; q < 4; ++q) SF[p*4+q] = By[p]*sx[q];
    {
        float By4 = By[3]*cy, By5 = By4*cy;
        #pragma unroll
        for (int q = 0; q < 4; ++q) { EXTv[q] = By4*sx[q]; EXTv[4+q] = By5*sx[q]; }
        #pragma unroll
        for (int p = 0; p < 4; ++p) { EXTv[8+p*2] = By[p]*sx4; EXTv[8+p*2+1] = By[p]*sx5; }
    }
    allred16(SF, lane);
    allred16(EXTv, lane);

    // ---- wd + u dot-products over this lane's 16 points ----
    float wdp = 0.f, pu = 0.f, puu = 0.f, uu = 0.f;
    #pragma unroll
    for (int k = 0; k < 16; ++k) {
        float x = px[k], ex = pex[k], y = py[k], ey = pey[k];
        float Axe[6], Aye[6];
        Axe[0]=ex; Aye[0]=ey;
        #pragma unroll
        for (int p = 1; p < 6; ++p) { Axe[p]=Axe[p-1]*x; Aye[p]=Aye[p-1]*y; }
        float x2 = x*x, y2 = y*y;
        float Axg[4] = {ex, 0.2f*ex*x, 0.02f*ex*x2, (1.0f/750.0f)*ex*x2*x};
        float Ayg[4] = {ey, 0.2f*ey*y, 0.02f*ey*y2, (1.0f/750.0f)*ey*y2*y};
        wdp += wd_point2(Axe, Aye, Axg, Ayg, u3[k], SF, EXTv);
        pu  += up[k]*u3[k];
        puu += up[k]*up[k];
        uu  += u3[k]*u3[k];
    }

    float part[10] = {nb, sud, sudb, svpv, svpvp, svv, pu, puu, uu, wdp};
    #pragma unroll
    for (int off = 32; off > 0; off >>= 1) {
        #pragma unroll
        for (int i = 0; i < 10; ++i) part[i] += __shfl_down(part[i], off, 64);
    }

    if (lane == 0) {
        float sc = part[1], Sbt = part[2];
        float denom = sc*sc + 1e-8f;
        float loss_pre = (sc/denom)*Sbt - (Sbt/denom)*sc;   // ~ 0 analytically
        float nvp = fmaxf(sqrtf(part[4]), 1e-8f);
        float nv  = fmaxf(sqrtf(part[5]), 1e-8f);
        float c1  = part[3]/(nvp*nv);
        float nup = fmaxf(sqrtf(part[7]), 1e-8f);
        float nu  = fmaxf(sqrtf(part[8]), 1e-8f);
        float c2  = part[6]/(nup*nu);
        float loss_i = loss_pre + (1.0f - c1) + (1.0f - c2);

        // publish partials (device-scope), last block sums -> d_out (R4-R7 proven)
        __hip_atomic_store(&ws[img*3 + 0], loss_i,  __ATOMIC_RELAXED, __HIP_MEMORY_SCOPE_AGENT);
        __hip_atomic_store(&ws[img*3 + 1], part[9], __ATOMIC_RELAXED, __HIP_MEMORY_SCOPE_AGENT);
        __hip_atomic_store(&ws[img*3 + 2], part[0], __ATOMIC_RELAXED, __HIP_MEMORY_SCOPE_AGENT);
        int prev = __hip_atomic_fetch_add(cnt, 1, __ATOMIC_ACQ_REL, __HIP_MEMORY_SCOPE_AGENT);
        if (prev == 7) {                     // last block: deterministic fixed-order sum
            float s0=0.f, s1=0.f, s2=0.f;
            for (int i = 0; i < 8; ++i) {
                s0 += __hip_atomic_load(&ws[i*3+0], __ATOMIC_RELAXED, __HIP_MEMORY_SCOPE_AGENT);
                s1 += __hip_atomic_load(&ws[i*3+1], __ATOMIC_RELAXED, __HIP_MEMORY_SCOPE_AGENT);
                s2 += __hip_atomic_load(&ws[i*3+2], __ATOMIC_RELAXED, __HIP_MEMORY_SCOPE_AGENT);
            }
            out[0] = s0; out[1] = s1; out[2] = s2;
        }
    }
}

extern "C" void kernel_launch(void* const* d_in, const int* in_sizes, int n_in,
                              void* d_out, int out_size, void* d_ws, size_t ws_size,
                              hipStream_t stream) {
    const float* nd  = (const float*)d_in[0];
    const float* ud  = (const float*)d_in[1];
    const float* pts = (const float*)d_in[2];
    const float* vp  = (const float*)d_in[3];
    float* out = (float*)d_out;
    float* ws  = (float*)d_ws;                  // 24 floats of per-image partials
    int*   cnt = (int*)((char*)d_ws + 256);     // completion counter

    hipMemsetAsync(cnt, 0, 4, stream);          // graph-safe memset node
    ot_main<<<dim3(8), dim3(64), 0, stream>>>(nd, ud, pts, vp, ws, cnt, out);
}